// Round 8
// baseline (556.189 us; speedup 1.0000x reference)
//
#include <hip/hip_runtime.h>
#include <hip/hip_bf16.h>
#include <math.h>

#define B_    8
#define L_    2048
#define HID   768
#define D2    384
#define NUV   1792
#define R_    16384
#define SCALE 0.08838834764831845f  // 128^-0.5

typedef __attribute__((ext_vector_type(8))) short bf16x8;
typedef __attribute__((ext_vector_type(4))) float f32x4;
typedef unsigned int uint32;
typedef unsigned short ushort;

static __device__ __forceinline__ uint32 bfr(float x) {
    uint32 u = __float_as_uint(x);
    return (u + 0x7FFFu + ((u >> 16) & 1u)) >> 16;
}
static __device__ __forceinline__ uint32 pk2(float lo, float hi) {
    return bfr(lo) | (bfr(hi) << 16);
}
static __device__ __forceinline__ float bf2f(ushort u) {
    return __uint_as_float(((uint32)u) << 16);
}
static __device__ __forceinline__ float silu_f(float x) { return x / (1.0f + __expf(-x)); }

// ---------------------------------------------------------------------------
// Weight pre-transform: Thi/Tlo[n][k] = bf16 hi/lo split of W[k][n]
// ---------------------------------------------------------------------------
__global__ __launch_bounds__(256) void conv_w(const float* __restrict__ W,
                                              ushort* __restrict__ Thi,
                                              ushort* __restrict__ Tlo,
                                              int K, int N)
{
    int idx = blockIdx.x * 256 + threadIdx.x;
    if (idx >= K * N) return;
    int n = idx / K, k = idx - n * K;
    float x = W[(size_t)k * N + n];
    uint32 h = bfr(x);
    float hf = __uint_as_float(h << 16);
    Thi[idx] = (ushort)h;
    Tlo[idx] = (ushort)bfr(x - hf);
}

// ---------------------------------------------------------------------------
// Split-bf16 MFMA GEMM (3-pass hi/lo). B pre-transposed+split [N][K] bf16.
// Block 512 thr (8 waves), tile 128x128, BK=64.
// EPI 0: C f32     EPI 1: GAU GEMM1 epilogue (u/v/qk by n0)
// ---------------------------------------------------------------------------
template<int EPI>
__global__ __launch_bounds__(512, 4) void gemm_mfma(
    const float* __restrict__ A, int lda,
    const ushort* __restrict__ BThi, const ushort* __restrict__ BTlo, int ldbt,
    float* __restrict__ C, int ldc,
    ushort* __restrict__ qk, ushort* __restrict__ vT, int K)
{
    __shared__ unsigned char As[128 * 256];
    __shared__ unsigned char Bs[128 * 256];

    const int t  = threadIdx.x;
    const int w  = t >> 6;
    const int l  = t & 63;
    const int g  = l >> 4;
    const int li = l & 15;
    const int wr = w >> 1;
    const int wc = w & 1;
    const int m0 = blockIdx.y * 128;
    const int n0 = blockIdx.x * 128;

    f32x4 acc[2][4];
#pragma unroll
    for (int i = 0; i < 2; ++i)
#pragma unroll
        for (int j = 0; j < 4; ++j) acc[i][j] = (f32x4){0.f, 0.f, 0.f, 0.f};

    for (int k0 = 0; k0 < K; k0 += 64) {
#pragma unroll
        for (int i = 0; i < 4; ++i) {
            int idx = t + i * 512;
            int r   = idx >> 4;
            int c16 = idx & 15;
            float4 v = *(const float4*)(A + (long long)(m0 + r) * lda + k0 + c16 * 4);
            uint2 h; h.x = pk2(v.x, v.y); h.y = pk2(v.z, v.w);
            float hx = __uint_as_float((h.x & 0xFFFFu) << 16), hy = __uint_as_float(h.x & 0xFFFF0000u);
            float hz = __uint_as_float((h.y & 0xFFFFu) << 16), hw = __uint_as_float(h.y & 0xFFFF0000u);
            uint2 lo; lo.x = pk2(v.x - hx, v.y - hy); lo.y = pk2(v.z - hz, v.w - hw);
            int sw = (c16 * 8) ^ ((r & 7) << 4);
            *(uint2*)&As[r * 256 + sw]       = h;
            *(uint2*)&As[r * 256 + 128 + sw] = lo;
        }
#pragma unroll
        for (int i = 0; i < 8; ++i) {
            int idx = t + i * 512;
            int c   = idx >> 5;
            int s8  = idx & 31;
            const ushort* src = (s8 < 16)
                ? (BThi + (long long)(n0 + c) * ldbt + k0 + s8 * 4)
                : (BTlo + (long long)(n0 + c) * ldbt + k0 + (s8 - 16) * 4);
            *(uint2*)&Bs[c * 256 + ((s8 * 8) ^ ((c & 7) << 4))] = *(const uint2*)src;
        }
        __syncthreads();

#pragma unroll
        for (int ks = 0; ks < 2; ++ks) {
            bf16x8 ah[2], al[2], bh[4], bl[4];
#pragma unroll
            for (int mi = 0; mi < 2; ++mi) {
                int row = wr * 32 + mi * 16 + li;
                int off = (ks * 64 + g * 16) ^ ((row & 7) << 4);
                ah[mi] = *(const bf16x8*)&As[row * 256 + off];
                al[mi] = *(const bf16x8*)&As[row * 256 + 128 + off];
            }
#pragma unroll
            for (int ni = 0; ni < 4; ++ni) {
                int col = wc * 64 + ni * 16 + li;
                int off = (ks * 64 + g * 16) ^ ((col & 7) << 4);
                bh[ni] = *(const bf16x8*)&Bs[col * 256 + off];
                bl[ni] = *(const bf16x8*)&Bs[col * 256 + 128 + off];
            }
#pragma unroll
            for (int mi = 0; mi < 2; ++mi)
#pragma unroll
                for (int ni = 0; ni < 4; ++ni) {
                    acc[mi][ni] = __builtin_amdgcn_mfma_f32_16x16x32_bf16(ah[mi], bh[ni], acc[mi][ni], 0, 0, 0);
                    acc[mi][ni] = __builtin_amdgcn_mfma_f32_16x16x32_bf16(ah[mi], bl[ni], acc[mi][ni], 0, 0, 0);
                    acc[mi][ni] = __builtin_amdgcn_mfma_f32_16x16x32_bf16(al[mi], bh[ni], acc[mi][ni], 0, 0, 0);
                }
        }
        __syncthreads();
    }

    if (EPI == 0) {
#pragma unroll
        for (int mi = 0; mi < 2; ++mi)
#pragma unroll
            for (int ni = 0; ni < 4; ++ni) {
                int col = n0 + wc * 64 + ni * 16 + li;
#pragma unroll
                for (int r = 0; r < 4; ++r) {
                    int row = m0 + wr * 32 + mi * 16 + g * 4 + r;
                    C[(long long)row * ldc + col] = acc[mi][ni][r];
                }
            }
    } else {
        if (n0 < 768) {
#pragma unroll
            for (int mi = 0; mi < 2; ++mi)
#pragma unroll
                for (int ni = 0; ni < 4; ++ni) {
                    int col = n0 + wc * 64 + ni * 16 + li;
#pragma unroll
                    for (int r = 0; r < 4; ++r) {
                        int row = m0 + wr * 32 + mi * 16 + g * 4 + r;
                        C[(long long)row * 768 + col] = silu_f(acc[mi][ni][r]);
                    }
                }
        } else if (n0 < 1536) {
            int bb = m0 >> 11;
            int llb = (m0 & 2047) + wr * 32 + g * 4;
#pragma unroll
            for (int mi = 0; mi < 2; ++mi) {
                int ll = llb + mi * 16;
#pragma unroll
                for (int ni = 0; ni < 4; ++ni) {
                    int cv = n0 + wc * 64 + ni * 16 + li - 768;
                    ushort* vb = vT + ((size_t)bb * 768 + cv) * 2048 + ll;
                    *(uint32*)(vb)     = pk2(silu_f(acc[mi][ni][0]), silu_f(acc[mi][ni][1]));
                    *(uint32*)(vb + 2) = pk2(silu_f(acc[mi][ni][2]), silu_f(acc[mi][ni][3]));
                }
            }
        } else {
#pragma unroll
            for (int mi = 0; mi < 2; ++mi)
#pragma unroll
                for (int ni = 0; ni < 4; ++ni) {
                    int qcol = n0 + wc * 64 + ni * 16 + li - 1536;
#pragma unroll
                    for (int r = 0; r < 4; ++r) {
                        int row = m0 + wr * 32 + mi * 16 + g * 4 + r;
                        qk[(size_t)row * 256 + qcol] = (ushort)bfr(acc[mi][ni][r]);
                    }
                }
        }
    }
}

// ---------------------------------------------------------------------------
// RoPE in place on bf16 qk buffer (q cols 0..127, k cols 128..255)
// ---------------------------------------------------------------------------
__global__ __launch_bounds__(128) void rope_bf(ushort* __restrict__ qk,
                                               const float* __restrict__ pos)
{
    int row = blockIdx.x;
    int lpos = row & (L_ - 1);
    int t = threadIdx.x;
    int j = t & 63;
    int isK = t >> 6;
    ushort* base = qk + (size_t)row * 256 + isK * 128;
    float s = pos[lpos * 256 + j];
    float c = pos[lpos * 256 + 64 + j];
    float x1 = bf2f(base[j]);
    float x2 = bf2f(base[64 + j]);
    base[j]      = (ushort)bfr(x1 * c - x2 * s);
    base[64 + j] = (ushort)bfr(x2 * c + x1 * s);
}

// ---------------------------------------------------------------------------
// MFMA flash attention v5 — swapped QK^T + key-permuted staging.
// QBLK=16 q-rows/block, 512 thr (8 waves), grid 1024.
// Swapped MFMA (A=K, B=Q) with key permutation p(k)=ct*16+g*4+r,
// k=32(ct&1)+8g+4(ct>>1)+r  ==>  lane (li,g) holds S[qrow=li][keys g*8-based]
// exactly matching the PV A-fragment layout: P never leaves registers.
// Softmax: local 16-max + 2 shuffles. K double-buffered LDS: 1 barrier/tile.
// ---------------------------------------------------------------------------
__global__ __launch_bounds__(512, 4) void fused_attn5(
    float* __restrict__ u_buf, const ushort* __restrict__ qk,
    const ushort* __restrict__ vT)
{
    __shared__ unsigned char KbB[2][64 * 256];   // K tile bf16 [pos][128d], swizzled, dbuf

    const int t  = threadIdx.x;
    const int w  = t >> 6;
    const int l  = t & 63;
    const int g  = l >> 4;
    const int li = l & 15;

    const int b  = blockIdx.x & 7;               // XCD-pinned batch
    const int qt = blockIdx.x >> 3;              // 0..127
    const long long rowQ0 = (long long)b * L_ + (long long)qt * 16;
    const long long rowB0 = (long long)b * L_;

    // ---- Q B-frags: lane (li,g) holds Q[qrow=li][d = ks*32 + g*8 ..+8] ----
    bf16x8 qf[4];
    {
        const ushort* qrow = qk + (rowQ0 + li) * 256;
#pragma unroll
        for (int ks = 0; ks < 4; ++ks)
            qf[ks] = *(const bf16x8*)&qrow[ks * 32 + g * 8];
    }

    float m_run = -3.0e38f, l_run = 0.0f;        // row li (replicated across g)

    f32x4 o[6];
#pragma unroll
    for (int ct = 0; ct < 6; ++ct) o[ct] = (f32x4){0.f, 0.f, 0.f, 0.f};

    const ushort* vrow = vT + ((size_t)b * 768 + w * 96 + li) * 2048 + g * 8;

    // ---- K staging: thread t stages original in-tile keys kr0=t>>4, kr0+32 ----
    const int kr0  = t >> 4;
    const int ks16 = t & 15;
    const int kr1  = kr0 + 32;
    // permuted destination position p(k)
    const int p0 = (((kr0 >> 2) & 1) * 2 + (kr0 >> 5)) * 16 + ((kr0 >> 3) & 3) * 4 + (kr0 & 3);
    const int p1 = (((kr1 >> 2) & 1) * 2 + (kr1 >> 5)) * 16 + ((kr1 >> 3) & 3) * 4 + (kr1 & 3);
    const int d0 = p0 * 256 + ((ks16 * 16) ^ ((p0 & 7) << 4));
    const int d1 = p1 * 256 + ((ks16 * 16) ^ ((p1 & 7) << 4));

    // prefetch K tile 0
    uint4 kreg0 = *(const uint4*)&qk[(rowB0 + kr0) * 256 + 128 + ks16 * 8];
    uint4 kreg1 = *(const uint4*)&qk[(rowB0 + kr1) * 256 + 128 + ks16 * 8];

    for (int jt = 0; jt < L_ / 64; ++jt) {
        unsigned char* Kb = &KbB[jt & 1][0];
        // ---- publish staged K tile into current buffer ----
        *(uint4*)&Kb[d0] = kreg0;
        *(uint4*)&Kb[d1] = kreg1;
        __syncthreads();    // K ready; prev buffer's readers long done (disjoint)

        // prefetch next K tile (hidden under compute)
        if (jt + 1 < L_ / 64) {
            kreg0 = *(const uint4*)&qk[(rowB0 + (jt + 1) * 64 + kr0) * 256 + 128 + ks16 * 8];
            kreg1 = *(const uint4*)&qk[(rowB0 + (jt + 1) * 64 + kr1) * 256 + 128 + ks16 * 8];
        }

        // ---- QK swapped: s[ct] = K_tile(ct) x Q  -> S[qrow=li][permuted keys] ----
        f32x4 s[4];
#pragma unroll
        for (int ct = 0; ct < 4; ++ct) {
            s[ct] = (f32x4){0.f, 0.f, 0.f, 0.f};
            const int krow = ct * 16 + li;
            const int rs   = (krow & 7) << 4;
#pragma unroll
            for (int ks = 0; ks < 4; ++ks) {
                bf16x8 kf = *(const bf16x8*)&Kb[krow * 256 + ((ks * 64 + g * 16) ^ rs)];
                s[ct] = __builtin_amdgcn_mfma_f32_16x16x32_bf16(kf, qf[ks], s[ct], 0, 0, 0);
            }
        }

        // ---- in-register online softmax for row li (16 vals/lane, x4 g-copies) ----
        float mx = s[0][0];
#pragma unroll
        for (int ct = 0; ct < 4; ++ct)
#pragma unroll
            for (int r = 0; r < 4; ++r) mx = fmaxf(mx, s[ct][r]);
        mx = fmaxf(mx, __shfl_xor(mx, 16));
        mx = fmaxf(mx, __shfl_xor(mx, 32));
        float mn = fmaxf(m_run, mx);
        float ratio = __expf(SCALE * (m_run - mn));
        m_run = mn;

        float p[4][4];
        float psum = 0.0f;
#pragma unroll
        for (int ct = 0; ct < 4; ++ct)
#pragma unroll
            for (int r = 0; r < 4; ++r) {
                p[ct][r] = __expf(SCALE * (s[ct][r] - mn));
                psum += p[ct][r];
            }
        psum += __shfl_xor(psum, 16);
        psum += __shfl_xor(psum, 32);
        l_run = l_run * ratio + psum;

        // ---- pack P directly into PV A-frags (keys already in frag order) ----
        union { bf16x8 v; uint32 u[4]; } pa0, pa1;
        pa0.u[0] = pk2(p[0][0], p[0][1]); pa0.u[1] = pk2(p[0][2], p[0][3]);
        pa0.u[2] = pk2(p[2][0], p[2][1]); pa0.u[3] = pk2(p[2][2], p[2][3]);
        pa1.u[0] = pk2(p[1][0], p[1][1]); pa1.u[1] = pk2(p[1][2], p[1][3]);
        pa1.u[2] = pk2(p[3][0], p[3][1]); pa1.u[3] = pk2(p[3][2], p[3][3]);

        // ---- rescale accumulators: ratio for rows g*4+r via tiny shuffles ----
        float rr[4];
#pragma unroll
        for (int r = 0; r < 4; ++r)
            rr[r] = __shfl(ratio, (l & 48) + g * 4 + r, 64);
#pragma unroll
        for (int ct = 0; ct < 6; ++ct)
#pragma unroll
            for (int r = 0; r < 4; ++r) o[ct][r] *= rr[r];

        // ---- PV: 96 private V-cols, V direct from L2, 2-deep pipeline ----
        {
            const ushort* vj = vrow + jt * 64;
            union U16 { uint4 u; bf16x8 bv; };
            U16 va, vb;
            va.u = *(const uint4*)(vj);
            vb.u = *(const uint4*)(vj + 32);
#pragma unroll
            for (int ct = 0; ct < 6; ++ct) {
                U16 na, nb;
                if (ct < 5) {
                    na.u = *(const uint4*)(vj + (size_t)(ct + 1) * 32768);
                    nb.u = *(const uint4*)(vj + (size_t)(ct + 1) * 32768 + 32);
                } else { na = va; nb = vb; }
                o[ct] = __builtin_amdgcn_mfma_f32_16x16x32_bf16(pa0.v, va.bv, o[ct], 0, 0, 0);
                o[ct] = __builtin_amdgcn_mfma_f32_16x16x32_bf16(pa1.v, vb.bv, o[ct], 0, 0, 0);
                va = na; vb = nb;
            }
        }
        // single barrier per tile: next publish goes to the OTHER buffer
    }

    // ---- finalize: /l (rows via shuffles), gate u in place ----
    {
        float inv[4];
#pragma unroll
        for (int r = 0; r < 4; ++r)
            inv[r] = 1.0f / __shfl(l_run, (l & 48) + g * 4 + r, 64);
#pragma unroll
        for (int r = 0; r < 4; ++r) {
            float* ub = u_buf + (rowQ0 + g * 4 + r) * 768;
#pragma unroll
            for (int ct = 0; ct < 6; ++ct) {
                int col = w * 96 + ct * 16 + li;
                ub[col] = o[ct][r] * inv[r] * ub[col];
            }
        }
    }
}

extern "C" void kernel_launch(void* const* d_in, const int* in_sizes, int n_in,
                              void* d_out, int out_size, void* d_ws, size_t ws_size,
                              hipStream_t stream)
{
    const float* x    = (const float*)d_in[0];   // [8,2048,384]
    const float* pos  = (const float*)d_in[1];   // [1,2048,256]
    const float* Wuv  = (const float*)d_in[2];   // [384,1792]
    const float* Wout = (const float*)d_in[3];   // [768,384]
    float* out = (float*)d_out;                  // [8,2048,384] f32

    float*  u_buf = (float*)d_ws;                        // 16384*768 f32
    ushort* qk    = (ushort*)(u_buf + (size_t)R_ * HID); // 16384*256 bf16
    ushort* vT    = qk + (size_t)R_ * 256;               // 8*768*2048 bf16
    ushort* WuvThi  = vT + (size_t)B_ * HID * L_;
    ushort* WuvTlo  = WuvThi + (size_t)NUV * D2;
    ushort* WoutThi = WuvTlo + (size_t)NUV * D2;
    ushort* WoutTlo = WoutThi + (size_t)D2 * HID;

    size_t need = ((size_t)R_ * HID) * 4 +
                  ((size_t)R_ * 256 + (size_t)B_ * HID * L_ +
                   2 * (size_t)NUV * D2 + 2 * (size_t)D2 * HID) * 2;
    if (ws_size < need) return;

    conv_w<<<dim3((D2 * NUV + 255) / 256), dim3(256), 0, stream>>>(Wuv, WuvThi, WuvTlo, D2, NUV);
    conv_w<<<dim3((HID * D2 + 255) / 256), dim3(256), 0, stream>>>(Wout, WoutThi, WoutTlo, HID, D2);

    gemm_mfma<1><<<dim3(NUV / 128, R_ / 128), dim3(512), 0, stream>>>(
        x, D2, WuvThi, WuvTlo, D2, u_buf, HID, qk, vT, D2);

    rope_bf<<<dim3(R_), dim3(128), 0, stream>>>(qk, pos);

    fused_attn5<<<dim3(1024), dim3(512), 0, stream>>>(u_buf, qk, vT);

    gemm_mfma<0><<<dim3(D2 / 128, R_ / 128), dim3(512), 0, stream>>>(
        u_buf, HID, WoutThi, WoutTlo, HID, out, D2, nullptr, nullptr, HID);
}

// Round 9
// 401.270 us; speedup vs baseline: 1.3861x; 1.3861x over previous
//
#include <hip/hip_runtime.h>
#include <hip/hip_bf16.h>
#include <math.h>

#define B_    8
#define L_    2048
#define HID   768
#define D2    384
#define NUV   1792
#define R_    16384
#define SCALE 0.08838834764831845f  // 128^-0.5

typedef __attribute__((ext_vector_type(8))) short bf16x8;
typedef __attribute__((ext_vector_type(4))) float f32x4;
typedef unsigned int uint32;
typedef unsigned short ushort;

static __device__ __forceinline__ uint32 bfr(float x) {
    uint32 u = __float_as_uint(x);
    return (u + 0x7FFFu + ((u >> 16) & 1u)) >> 16;
}
static __device__ __forceinline__ uint32 pk2(float lo, float hi) {
    return bfr(lo) | (bfr(hi) << 16);
}
static __device__ __forceinline__ float bf2f(ushort u) {
    return __uint_as_float(((uint32)u) << 16);
}
static __device__ __forceinline__ float silu_f(float x) { return x / (1.0f + __expf(-x)); }

// ---------------------------------------------------------------------------
// Weight pre-transform: Thi/Tlo[n][k] = bf16 hi/lo split of W[k][n]
// ---------------------------------------------------------------------------
__global__ __launch_bounds__(256) void conv_w(const float* __restrict__ W,
                                              ushort* __restrict__ Thi,
                                              ushort* __restrict__ Tlo,
                                              int K, int N)
{
    int idx = blockIdx.x * 256 + threadIdx.x;
    if (idx >= K * N) return;
    int n = idx / K, k = idx - n * K;
    float x = W[(size_t)k * N + n];
    uint32 h = bfr(x);
    float hf = __uint_as_float(h << 16);
    Thi[idx] = (ushort)h;
    Tlo[idx] = (ushort)bfr(x - hf);
}

// ---------------------------------------------------------------------------
// Split-bf16 MFMA GEMM (3-pass hi/lo). B pre-transposed+split [N][K] bf16.
// Block 512 thr (8 waves), tile 128x128, BK=64.
// EPI 0: C f32     EPI 1: GAU GEMM1 epilogue (u/v/qk by n0)
// ---------------------------------------------------------------------------
template<int EPI>
__global__ __launch_bounds__(512, 4) void gemm_mfma(
    const float* __restrict__ A, int lda,
    const ushort* __restrict__ BThi, const ushort* __restrict__ BTlo, int ldbt,
    float* __restrict__ C, int ldc,
    ushort* __restrict__ qk, ushort* __restrict__ vT, int K)
{
    __shared__ unsigned char As[128 * 256];
    __shared__ unsigned char Bs[128 * 256];

    const int t  = threadIdx.x;
    const int w  = t >> 6;
    const int l  = t & 63;
    const int g  = l >> 4;
    const int li = l & 15;
    const int wr = w >> 1;
    const int wc = w & 1;
    const int m0 = blockIdx.y * 128;
    const int n0 = blockIdx.x * 128;

    f32x4 acc[2][4];
#pragma unroll
    for (int i = 0; i < 2; ++i)
#pragma unroll
        for (int j = 0; j < 4; ++j) acc[i][j] = (f32x4){0.f, 0.f, 0.f, 0.f};

    for (int k0 = 0; k0 < K; k0 += 64) {
#pragma unroll
        for (int i = 0; i < 4; ++i) {
            int idx = t + i * 512;
            int r   = idx >> 4;
            int c16 = idx & 15;
            float4 v = *(const float4*)(A + (long long)(m0 + r) * lda + k0 + c16 * 4);
            uint2 h; h.x = pk2(v.x, v.y); h.y = pk2(v.z, v.w);
            float hx = __uint_as_float((h.x & 0xFFFFu) << 16), hy = __uint_as_float(h.x & 0xFFFF0000u);
            float hz = __uint_as_float((h.y & 0xFFFFu) << 16), hw = __uint_as_float(h.y & 0xFFFF0000u);
            uint2 lo; lo.x = pk2(v.x - hx, v.y - hy); lo.y = pk2(v.z - hz, v.w - hw);
            int sw = (c16 * 8) ^ ((r & 7) << 4);
            *(uint2*)&As[r * 256 + sw]       = h;
            *(uint2*)&As[r * 256 + 128 + sw] = lo;
        }
#pragma unroll
        for (int i = 0; i < 8; ++i) {
            int idx = t + i * 512;
            int c   = idx >> 5;
            int s8  = idx & 31;
            const ushort* src = (s8 < 16)
                ? (BThi + (long long)(n0 + c) * ldbt + k0 + s8 * 4)
                : (BTlo + (long long)(n0 + c) * ldbt + k0 + (s8 - 16) * 4);
            *(uint2*)&Bs[c * 256 + ((s8 * 8) ^ ((c & 7) << 4))] = *(const uint2*)src;
        }
        __syncthreads();

#pragma unroll
        for (int ks = 0; ks < 2; ++ks) {
            bf16x8 ah[2], al[2], bh[4], bl[4];
#pragma unroll
            for (int mi = 0; mi < 2; ++mi) {
                int row = wr * 32 + mi * 16 + li;
                int off = (ks * 64 + g * 16) ^ ((row & 7) << 4);
                ah[mi] = *(const bf16x8*)&As[row * 256 + off];
                al[mi] = *(const bf16x8*)&As[row * 256 + 128 + off];
            }
#pragma unroll
            for (int ni = 0; ni < 4; ++ni) {
                int col = wc * 64 + ni * 16 + li;
                int off = (ks * 64 + g * 16) ^ ((col & 7) << 4);
                bh[ni] = *(const bf16x8*)&Bs[col * 256 + off];
                bl[ni] = *(const bf16x8*)&Bs[col * 256 + 128 + off];
            }
#pragma unroll
            for (int mi = 0; mi < 2; ++mi)
#pragma unroll
                for (int ni = 0; ni < 4; ++ni) {
                    acc[mi][ni] = __builtin_amdgcn_mfma_f32_16x16x32_bf16(ah[mi], bh[ni], acc[mi][ni], 0, 0, 0);
                    acc[mi][ni] = __builtin_amdgcn_mfma_f32_16x16x32_bf16(ah[mi], bl[ni], acc[mi][ni], 0, 0, 0);
                    acc[mi][ni] = __builtin_amdgcn_mfma_f32_16x16x32_bf16(al[mi], bh[ni], acc[mi][ni], 0, 0, 0);
                }
        }
        __syncthreads();
    }

    if (EPI == 0) {
#pragma unroll
        for (int mi = 0; mi < 2; ++mi)
#pragma unroll
            for (int ni = 0; ni < 4; ++ni) {
                int col = n0 + wc * 64 + ni * 16 + li;
#pragma unroll
                for (int r = 0; r < 4; ++r) {
                    int row = m0 + wr * 32 + mi * 16 + g * 4 + r;
                    C[(long long)row * ldc + col] = acc[mi][ni][r];
                }
            }
    } else {
        if (n0 < 768) {
#pragma unroll
            for (int mi = 0; mi < 2; ++mi)
#pragma unroll
                for (int ni = 0; ni < 4; ++ni) {
                    int col = n0 + wc * 64 + ni * 16 + li;
#pragma unroll
                    for (int r = 0; r < 4; ++r) {
                        int row = m0 + wr * 32 + mi * 16 + g * 4 + r;
                        C[(long long)row * 768 + col] = silu_f(acc[mi][ni][r]);
                    }
                }
        } else if (n0 < 1536) {
            int bb = m0 >> 11;
            int llb = (m0 & 2047) + wr * 32 + g * 4;
#pragma unroll
            for (int mi = 0; mi < 2; ++mi) {
                int ll = llb + mi * 16;
#pragma unroll
                for (int ni = 0; ni < 4; ++ni) {
                    int cv = n0 + wc * 64 + ni * 16 + li - 768;
                    ushort* vb = vT + ((size_t)bb * 768 + cv) * 2048 + ll;
                    *(uint32*)(vb)     = pk2(silu_f(acc[mi][ni][0]), silu_f(acc[mi][ni][1]));
                    *(uint32*)(vb + 2) = pk2(silu_f(acc[mi][ni][2]), silu_f(acc[mi][ni][3]));
                }
            }
        } else {
#pragma unroll
            for (int mi = 0; mi < 2; ++mi)
#pragma unroll
                for (int ni = 0; ni < 4; ++ni) {
                    int qcol = n0 + wc * 64 + ni * 16 + li - 1536;
#pragma unroll
                    for (int r = 0; r < 4; ++r) {
                        int row = m0 + wr * 32 + mi * 16 + g * 4 + r;
                        qk[(size_t)row * 256 + qcol] = (ushort)bfr(acc[mi][ni][r]);
                    }
                }
        }
    }
}

// ---------------------------------------------------------------------------
// RoPE in place on bf16 qk buffer (q cols 0..127, k cols 128..255)
// ---------------------------------------------------------------------------
__global__ __launch_bounds__(128) void rope_bf(ushort* __restrict__ qk,
                                               const float* __restrict__ pos)
{
    int row = blockIdx.x;
    int lpos = row & (L_ - 1);
    int t = threadIdx.x;
    int j = t & 63;
    int isK = t >> 6;
    ushort* base = qk + (size_t)row * 256 + isK * 128;
    float s = pos[lpos * 256 + j];
    float c = pos[lpos * 256 + 64 + j];
    float x1 = bf2f(base[j]);
    float x2 = bf2f(base[64 + j]);
    base[j]      = (ushort)bfr(x1 * c - x2 * s);
    base[64 + j] = (ushort)bfr(x2 * c + x1 * s);
}

// ---------------------------------------------------------------------------
// MFMA flash attention v6 = r5-best (fused_attn2) + latency fixes:
//  * K prefetched 1 tile ahead into regs, published to LDS at tile top
//  * V loads issued EARLY (ct0..2 after barrier A, hidden under QK+softmax),
//    3-deep rolling rotation through PV (static names)
//  * s_setprio(1) around MFMA clusters
//  * QK accumulation split into 2 chains of 2 (halved dep depth)
// Block: 32 q-rows, 512 thr (8 waves), grid 512 (XCD-pinned).
// ---------------------------------------------------------------------------
__global__ __launch_bounds__(512) void fused_attn6(
    float* __restrict__ u_buf, const ushort* __restrict__ qk,
    const ushort* __restrict__ vT)
{
    __shared__ unsigned char KbB[64 * 256];   // K tile bf16 [64][128], swizzled
    __shared__ float Ps[32][68];              // S-tile f32, padded
    __shared__ unsigned char PbB[32 * 128];   // P bf16 [32][64], swizzled
    __shared__ float mrun[32], lrun[32], ratio_s[32];

    const int t  = threadIdx.x;
    const int w  = t >> 6;
    const int l  = t & 63;
    const int g  = l >> 4;
    const int li = l & 15;

    const int b  = blockIdx.x & 7;
    const int qt = blockIdx.x >> 3;           // 0..63
    const long long rowQ0 = (long long)b * L_ + (long long)qt * 32;
    const long long rowB0 = (long long)b * L_;

    const int rw = w & 1;    // QK S row-tile
    const int cw = w >> 1;   // QK S col-tile

    // Q A-fragments from bf16 qk (once)
    bf16x8 qf[4];
    {
        const ushort* qrow = qk + (rowQ0 + rw * 16 + li) * 256;
#pragma unroll
        for (int ks = 0; ks < 4; ++ks)
            qf[ks] = *(const bf16x8*)&qrow[ks * 32 + g * 8];
    }
    if (t < 32) { mrun[t] = -3.0e38f; lrun[t] = 0.0f; }

    f32x4 o[2][6];
#pragma unroll
    for (int rt = 0; rt < 2; ++rt)
#pragma unroll
        for (int ct = 0; ct < 6; ++ct)
            o[rt][ct] = (f32x4){0.f, 0.f, 0.f, 0.f};

    const ushort* vrow = vT + ((size_t)b * 768 + w * 96 + li) * 2048 + g * 8;

    // K staging: thread t stages rows kr0 = t>>4 and kr0+32, 16B col chunk
    const int kr0  = t >> 4;
    const int ks16 = t & 15;
    const int kr1  = kr0 + 32;
    const int d0 = kr0 * 256 + ((ks16 * 16) ^ ((kr0 & 7) << 4));
    const int d1 = kr1 * 256 + ((ks16 * 16) ^ ((kr1 & 7) << 4));

    // prefetch K tile 0
    uint4 kreg0 = *(const uint4*)&qk[(rowB0 + kr0) * 256 + 128 + ks16 * 8];
    uint4 kreg1 = *(const uint4*)&qk[(rowB0 + kr1) * 256 + 128 + ks16 * 8];

    union U16 { uint4 u; bf16x8 bv; };

    for (int jt = 0; jt < L_ / 64; ++jt) {
        // ---- publish staged K tile ----
        *(uint4*)&KbB[d0] = kreg0;
        *(uint4*)&KbB[d1] = kreg1;
        __syncthreads();   // (A) K ready

        // prefetch next K tile
        if (jt + 1 < L_ / 64) {
            kreg0 = *(const uint4*)&qk[(rowB0 + (jt + 1) * 64 + kr0) * 256 + 128 + ks16 * 8];
            kreg1 = *(const uint4*)&qk[(rowB0 + (jt + 1) * 64 + kr1) * 256 + 128 + ks16 * 8];
        }

        // ---- EARLY V issue: ct = 0,1,2 (hidden under QK + softmax) ----
        const ushort* vj = vrow + jt * 64;
        U16 va0, vb0, va1, vb1, va2, vb2;
        va0.u = *(const uint4*)(vj);
        vb0.u = *(const uint4*)(vj + 32);
        va1.u = *(const uint4*)(vj + 32768);
        vb1.u = *(const uint4*)(vj + 32768 + 32);
        va2.u = *(const uint4*)(vj + 65536);
        vb2.u = *(const uint4*)(vj + 65536 + 32);

        // ---- QK: one 16x16 S-tile per wave, K=128, 2 chains of 2 ----
        {
            f32x4 sa = {0.f, 0.f, 0.f, 0.f};
            f32x4 sb = {0.f, 0.f, 0.f, 0.f};
            const int krow = cw * 16 + li;
            const int rs = (krow & 7) << 4;
            bf16x8 kf0 = *(const bf16x8*)&KbB[krow * 256 + ((0 * 64 + g * 16) ^ rs)];
            bf16x8 kf1 = *(const bf16x8*)&KbB[krow * 256 + ((1 * 64 + g * 16) ^ rs)];
            bf16x8 kf2 = *(const bf16x8*)&KbB[krow * 256 + ((2 * 64 + g * 16) ^ rs)];
            bf16x8 kf3 = *(const bf16x8*)&KbB[krow * 256 + ((3 * 64 + g * 16) ^ rs)];
            __builtin_amdgcn_s_setprio(1);
            sa = __builtin_amdgcn_mfma_f32_16x16x32_bf16(qf[0], kf0, sa, 0, 0, 0);
            sb = __builtin_amdgcn_mfma_f32_16x16x32_bf16(qf[1], kf1, sb, 0, 0, 0);
            sa = __builtin_amdgcn_mfma_f32_16x16x32_bf16(qf[2], kf2, sa, 0, 0, 0);
            sb = __builtin_amdgcn_mfma_f32_16x16x32_bf16(qf[3], kf3, sb, 0, 0, 0);
            __builtin_amdgcn_s_setprio(0);
#pragma unroll
            for (int r = 0; r < 4; ++r)
                Ps[rw * 16 + g * 4 + r][cw * 16 + li] = sa[r] + sb[r];
        }
        __syncthreads();   // (B) Ps ready

        // ---- online softmax: 16 lanes/row, 4 consecutive cols each ----
        {
            int row = t >> 4;
            float4 x4 = *(const float4*)&Ps[row][li * 4];
            float mx = fmaxf(fmaxf(x4.x, x4.y), fmaxf(x4.z, x4.w));
#pragma unroll
            for (int off = 8; off >= 1; off >>= 1) mx = fmaxf(mx, __shfl_xor(mx, off));
            float mo = mrun[row];
            float mn = fmaxf(mo, mx);
            float p0 = __expf(SCALE * (x4.x - mn)), p1 = __expf(SCALE * (x4.y - mn));
            float p2 = __expf(SCALE * (x4.z - mn)), p3 = __expf(SCALE * (x4.w - mn));
            float ps = p0 + p1 + p2 + p3;
#pragma unroll
            for (int off = 8; off >= 1; off >>= 1) ps += __shfl_xor(ps, off);
            if (li == 0) {
                float rt_ = __expf(SCALE * (mo - mn));
                ratio_s[row] = rt_;
                lrun[row] = lrun[row] * rt_ + ps;
                mrun[row] = mn;
            }
            uint2 pw; pw.x = pk2(p0, p1); pw.y = pk2(p2, p3);
            *(uint2*)&PbB[row * 128 + ((li * 8) ^ ((row & 7) << 4))] = pw;
        }
        __syncthreads();   // (C) Pb, ratio ready

        // ---- PV: rescale, then P@V with 3-deep rolling V pipeline ----
        {
            float rr[2][4];
#pragma unroll
            for (int rt = 0; rt < 2; ++rt)
#pragma unroll
                for (int r = 0; r < 4; ++r)
                    rr[rt][r] = ratio_s[rt * 16 + g * 4 + r];
#pragma unroll
            for (int rt = 0; rt < 2; ++rt)
#pragma unroll
                for (int ct = 0; ct < 6; ++ct)
#pragma unroll
                    for (int r = 0; r < 4; ++r)
                        o[rt][ct][r] *= rr[rt][r];

            bf16x8 pa00 = *(const bf16x8*)&PbB[li * 128 + ((0 * 64 + g * 16) ^ ((li & 7) << 4))];
            bf16x8 pa01 = *(const bf16x8*)&PbB[li * 128 + ((1 * 64 + g * 16) ^ ((li & 7) << 4))];
            bf16x8 pa10 = *(const bf16x8*)&PbB[(16 + li) * 128 + ((0 * 64 + g * 16) ^ ((li & 7) << 4))];
            bf16x8 pa11 = *(const bf16x8*)&PbB[(16 + li) * 128 + ((1 * 64 + g * 16) ^ ((li & 7) << 4))];

#define PV_STEP(CT, VA, VB) \
            o[0][CT] = __builtin_amdgcn_mfma_f32_16x16x32_bf16(pa00, VA.bv, o[0][CT], 0, 0, 0); \
            o[0][CT] = __builtin_amdgcn_mfma_f32_16x16x32_bf16(pa01, VB.bv, o[0][CT], 0, 0, 0); \
            o[1][CT] = __builtin_amdgcn_mfma_f32_16x16x32_bf16(pa10, VA.bv, o[1][CT], 0, 0, 0); \
            o[1][CT] = __builtin_amdgcn_mfma_f32_16x16x32_bf16(pa11, VB.bv, o[1][CT], 0, 0, 0);

            __builtin_amdgcn_s_setprio(1);
            PV_STEP(0, va0, vb0)
            va0.u = *(const uint4*)(vj + (size_t)3 * 32768);
            vb0.u = *(const uint4*)(vj + (size_t)3 * 32768 + 32);
            PV_STEP(1, va1, vb1)
            va1.u = *(const uint4*)(vj + (size_t)4 * 32768);
            vb1.u = *(const uint4*)(vj + (size_t)4 * 32768 + 32);
            PV_STEP(2, va2, vb2)
            va2.u = *(const uint4*)(vj + (size_t)5 * 32768);
            vb2.u = *(const uint4*)(vj + (size_t)5 * 32768 + 32);
            PV_STEP(3, va0, vb0)
            PV_STEP(4, va1, vb1)
            PV_STEP(5, va2, vb2)
            __builtin_amdgcn_s_setprio(0);
#undef PV_STEP
        }
        // next K publish is safe: all waves passed (C) => QK of this tile done
    }

    // ---- finalize: /l, gate u in place (f32) ----
    {
        float inv[2][4];
#pragma unroll
        for (int rt = 0; rt < 2; ++rt)
#pragma unroll
            for (int r = 0; r < 4; ++r)
                inv[rt][r] = 1.0f / lrun[rt * 16 + g * 4 + r];
#pragma unroll
        for (int rt = 0; rt < 2; ++rt) {
#pragma unroll
            for (int r = 0; r < 4; ++r) {
                float* ub = u_buf + (rowQ0 + rt * 16 + g * 4 + r) * 768;
#pragma unroll
                for (int ct = 0; ct < 6; ++ct) {
                    int col = w * 96 + ct * 16 + li;
                    ub[col] = o[rt][ct][r] * inv[rt][r] * ub[col];
                }
            }
        }
    }
}

extern "C" void kernel_launch(void* const* d_in, const int* in_sizes, int n_in,
                              void* d_out, int out_size, void* d_ws, size_t ws_size,
                              hipStream_t stream)
{
    const float* x    = (const float*)d_in[0];   // [8,2048,384]
    const float* pos  = (const float*)d_in[1];   // [1,2048,256]
    const float* Wuv  = (const float*)d_in[2];   // [384,1792]
    const float* Wout = (const float*)d_in[3];   // [768,384]
    float* out = (float*)d_out;                  // [8,2048,384] f32

    float*  u_buf = (float*)d_ws;                        // 16384*768 f32
    ushort* qk    = (ushort*)(u_buf + (size_t)R_ * HID); // 16384*256 bf16
    ushort* vT    = qk + (size_t)R_ * 256;               // 8*768*2048 bf16
    ushort* WuvThi  = vT + (size_t)B_ * HID * L_;
    ushort* WuvTlo  = WuvThi + (size_t)NUV * D2;
    ushort* WoutThi = WuvTlo + (size_t)NUV * D2;
    ushort* WoutTlo = WoutThi + (size_t)D2 * HID;

    size_t need = ((size_t)R_ * HID) * 4 +
                  ((size_t)R_ * 256 + (size_t)B_ * HID * L_ +
                   2 * (size_t)NUV * D2 + 2 * (size_t)D2 * HID) * 2;
    if (ws_size < need) return;

    conv_w<<<dim3((D2 * NUV + 255) / 256), dim3(256), 0, stream>>>(Wuv, WuvThi, WuvTlo, D2, NUV);
    conv_w<<<dim3((HID * D2 + 255) / 256), dim3(256), 0, stream>>>(Wout, WoutThi, WoutTlo, HID, D2);

    gemm_mfma<1><<<dim3(NUV / 128, R_ / 128), dim3(512), 0, stream>>>(
        x, D2, WuvThi, WuvTlo, D2, u_buf, HID, qk, vT, D2);

    rope_bf<<<dim3(R_), dim3(128), 0, stream>>>(qk, pos);

    fused_attn6<<<dim3(512), dim3(512), 0, stream>>>(u_buf, qk, vT);

    gemm_mfma<0><<<dim3(D2 / 128, R_ / 128), dim3(512), 0, stream>>>(
        u_buf, HID, WoutThi, WoutTlo, HID, out, D2, nullptr, nullptr, HID);
}